// Round 11
// baseline (483.433 us; speedup 1.0000x reference)
//
#include <hip/hip_runtime.h>
#include <math.h>

#define NPIX 262144      // 512*512
#define T_B 4
#define T_C 20
#define T_K 16
#define TILE 256         // k-depth per LDS tile
#define XB 128           // x-blocks per batch; 512 blocks total -> 2 blocks/CU
#define NTILES (NPIX / TILE / XB)   // 8
#define NCOPY 8          // atomic contention spreading
#define GRAM_F 960       // 4b * 15 pair-blocks * 16
#define PART_F 1200      // + 4b * 20c * 3 slots

__device__ __forceinline__ float wave_red(float v) {
#pragma unroll
  for (int off = 32; off > 0; off >>= 1) v += __shfl_xor(v, off, 64);
  return v;
}
// packed index of 4x4 channel block (I,J), I<=J, upper-tri of 5x5 grid; pb_idx(I,J)==wv
__device__ __forceinline__ int pb_idx(int I, int J) { return I * (11 - I) / 2 + (J - I); }

// One pass over X (+Y for c<16): gram 20x20 per batch AND all linear stats.
// v3: XB=128 (2 blocks/CU) + double-buffered LDS (one barrier per tile),
// NO min-wave launch bound: v2's (960,8) forced VGPR 44->32 and spilled
// 164 MB of scratch per dispatch (R8 counters). Natural allocation ~44-48
// VGPR still permits 8 waves/SIMD (<=64-VGPR step), LDS 40KB*2 <= 160KB.
__global__ __launch_bounds__(960) void fused_kernel(const float* __restrict__ X,
                                                    const int* __restrict__ Y,
                                                    float* __restrict__ pw) {
  __shared__ float xs[2][T_C][TILE];  // 40 KB (double-buffered)
  const int tid = threadIdx.x, wv = tid >> 6, ln = tid & 63;
  const int b = blockIdx.y, xb = blockIdx.x;
  const int copy = xb & (NCOPY - 1);
  const float* Xb = X + (size_t)b * T_C * NPIX;
  const int*   Yb = Y + (size_t)b * T_C * NPIX;

  int I = 0, w = wv;
  while (w >= 5 - I) { w -= 5 - I; ++I; }
  const int J = I + w, rowA = 4 * I, rowB = 4 * J;

  const int c0 = wv;              // 0..14 (always <16: Y needed)
  const bool has2 = (wv < 5);
  const int c1 = 15 + wv;         // 15..19
  const bool y1 = (wv == 0);      // c1==15 still needs Y

  const float* x0p = Xb + (size_t)c0 * NPIX + ln * 4;
  const int*   y0p = Yb + (size_t)c0 * NPIX + ln * 4;
  const float* x1p = Xb + (size_t)c1 * NPIX + ln * 4;
  const int*   y1p = Yb + (size_t)c1 * NPIX + ln * 4;

  float acc[16];
#pragma unroll
  for (int m = 0; m < 16; ++m) acc[m] = 0.f;
  float sxy0 = 0.f, sy0 = 0.f, sb0 = 0.f;
  float sxy1 = 0.f, sy1 = 0.f, sb1 = 0.f, sx1 = 0.f;

  // prologue loads (tile 0 of this block)
  int k0 = xb * TILE;
  float4 xr0 = *(const float4*)(x0p + k0);
  int4   yr0 = *(const int4*)(y0p + k0);
  float4 xr1; int4 yr1;
  if (has2) xr1 = *(const float4*)(x1p + k0);
  if (y1)   yr1 = *(const int4*)(y1p + k0);

  for (int t = 0; t < NTILES; ++t) {
    float (*buf)[TILE] = xs[t & 1];
    // write staged regs to LDS buffer t&1
    *(float4*)&buf[c0][ln * 4] = xr0;
    if (has2) *(float4*)&buf[c1][ln * 4] = xr1;

    // stats from the staged registers (free ride on the staging pass)
    {
      float xv[4] = {xr0.x, xr0.y, xr0.z, xr0.w};
      int   yv[4] = {yr0.x, yr0.y, yr0.z, yr0.w};
#pragma unroll
      for (int u = 0; u < 4; ++u) {
        float fy = (float)yv[u];
        sxy0 = fmaf(fy, xv[u], sxy0);
        sy0 += fy;
        // y*log(x) + (1-y)*log1p(-x), y in {0,1}  ==  log(y ? x : 1-x)
        sb0 += __logf(yv[u] ? xv[u] : 1.f - xv[u]);
      }
    }
    if (has2) {
      float xv[4] = {xr1.x, xr1.y, xr1.z, xr1.w};
      if (y1) {
        int yv[4] = {yr1.x, yr1.y, yr1.z, yr1.w};
#pragma unroll
        for (int u = 0; u < 4; ++u) {
          float fy = (float)yv[u];
          sxy1 = fmaf(fy, xv[u], sxy1);
          sy1 += fy;
          sb1 += __logf(yv[u] ? xv[u] : 1.f - xv[u]);
        }
      } else {
        sx1 += (xv[0] + xv[1]) + (xv[2] + xv[3]);
      }
    }

    // issue next tile's global loads (latency hides under barrier+gram,
    // and under the co-resident block)
    if (t + 1 < NTILES) {
      int k0n = (xb + (t + 1) * XB) * TILE;
      xr0 = *(const float4*)(x0p + k0n);
      yr0 = *(const int4*)(y0p + k0n);
      if (has2) xr1 = *(const float4*)(x1p + k0n);
      if (y1)   yr1 = *(const int4*)(y1p + k0n);
    }
    __syncthreads();  // single barrier per tile: buf[t&1] complete.
    // Hazard note: iter t's reads of buf[t&1] are separated from iter t+2's
    // rewrite of buf[t&1] by the barrier in iter t+1.

    // gram compute on current LDS tile
    const int k = ln * 4;
    float4 av[4], bv[4];
#pragma unroll
    for (int r = 0; r < 4; ++r) av[r] = *(const float4*)&buf[rowA + r][k];
#pragma unroll
    for (int r = 0; r < 4; ++r) bv[r] = *(const float4*)&buf[rowB + r][k];
#pragma unroll
    for (int r = 0; r < 4; ++r)
#pragma unroll
      for (int q = 0; q < 4; ++q)
        acc[r * 4 + q] += (av[r].x * bv[q].x + av[r].y * bv[q].y) +
                          (av[r].z * bv[q].z + av[r].w * bv[q].w);
  }

  // partial outputs: 8-way copy spreading => 16 writers per address
  float* pc = pw + copy * PART_F;
#pragma unroll
  for (int m = 0; m < 16; ++m) {
    float v = wave_red(acc[m]);
    if (ln == 0) atomicAdd(&pc[(b * 15 + wv) * 16 + m], v);
  }
  float v;
  v = wave_red(sxy0); if (ln == 0) atomicAdd(&pc[GRAM_F + (b * T_C + c0) * 3 + 0], v);
  v = wave_red(sy0);  if (ln == 0) atomicAdd(&pc[GRAM_F + (b * T_C + c0) * 3 + 1], v);
  v = wave_red(sb0);  if (ln == 0) atomicAdd(&pc[GRAM_F + (b * T_C + c0) * 3 + 2], v);
  if (has2) {
    if (y1) {
      v = wave_red(sxy1); if (ln == 0) atomicAdd(&pc[GRAM_F + (b * T_C + c1) * 3 + 0], v);
      v = wave_red(sy1);  if (ln == 0) atomicAdd(&pc[GRAM_F + (b * T_C + c1) * 3 + 1], v);
      v = wave_red(sb1);  if (ln == 0) atomicAdd(&pc[GRAM_F + (b * T_C + c1) * 3 + 2], v);
    } else {
      v = wave_red(sx1);  if (ln == 0) atomicAdd(&pc[GRAM_F + (b * T_C + c1) * 3 + 0], v);
    }
  }
}

// ---------------- finalize: sum 8 copies (float4), compute 4 scalars ----------------
__global__ __launch_bounds__(64) void finalize_kernel(const float* __restrict__ pw,
                                                      float* __restrict__ out) {
  __shared__ __align__(16) float red[PART_F];
  const int ln = threadIdx.x;
  for (int o4 = ln; o4 < PART_F / 4; o4 += 64) {
    float4 s = {0.f, 0.f, 0.f, 0.f};
#pragma unroll
    for (int c8 = 0; c8 < NCOPY; ++c8) {
      float4 vv = *(const float4*)(pw + c8 * PART_F + o4 * 4);
      s.x += vv.x; s.y += vv.y; s.z += vv.z; s.w += vv.w;
    }
    *(float4*)&red[o4 * 4] = s;
  }
  __syncthreads();
  const float invBN = 1.f / (4.f * 262144.f);

  // loss3
  float l3p = 0.f;
  for (int ij = ln; ij < 400; ij += 64) {
    const int i = ij / 20, j = ij % 20;
    if (i == j) continue;
    const int Ii = i >> 2, ri = i & 3, Jj = j >> 2, rj = j & 3;
    float sum = 0.f;
#pragma unroll
    for (int b = 0; b < 4; ++b) {
      float g = (Ii <= Jj) ? red[(b * 15 + pb_idx(Ii, Jj)) * 16 + ri * 4 + rj]
                           : red[(b * 15 + pb_idx(Jj, Ii)) * 16 + rj * 4 + ri];
      float si = red[(b * 15 + pb_idx(Ii, Ii)) * 16 + ri * 5];
      float sj = red[(b * 15 + pb_idx(Jj, Jj)) * 16 + rj * 5];
      sum += (g + 1.f) / (si + sj + 1.f);
    }
    l3p += sum * 0.25f;
  }
  const float l3 = wave_red(l3p) / 380.f;

  // loss1: dice + bce, c<16
  float l1p = 0.f;
  if (ln < 16) {
    const int c = ln, Ic = c >> 2, rc = c & 3;
    float d = 0.f, bsum = 0.f;
#pragma unroll
    for (int b = 0; b < 4; ++b) {
      float num = red[GRAM_F + (b * T_C + c) * 3 + 0] + 1.f;
      float s = red[(b * 15 + pb_idx(Ic, Ic)) * 16 + rc * 5];      // sum x^2 (gram diag)
      float den = s + red[GRAM_F + (b * T_C + c) * 3 + 1] + 1.f;   // + sum y
      d += 1.f - num / den;
      bsum += red[GRAM_F + (b * T_C + c) * 3 + 2];
    }
    l1p = d * 0.25f - bsum * invBN;
  }
  const float l1 = wave_red(l1p) * (1.f / 16.f);

  // loss2: c>=16
  float l2p = 0.f;
  if (ln >= 16 && ln < 20) {
    float s = 0.f;
#pragma unroll
    for (int b = 0; b < 4; ++b) s += red[GRAM_F + (b * T_C + ln) * 3 + 0];
    float m = s * invBN;
    float vv = fminf(fmaxf(m * 50.f, 0.f), 1.f);
    l2p = -logf(vv);
  }
  const float l2 = wave_red(l2p) * 0.25f;

  if (ln == 0) {
    out[1] = l1; out[2] = l2; out[3] = l3;
    out[0] = 0.1f * (l1 + l2 + l3);
  }
}

extern "C" void kernel_launch(void* const* d_in, const int* in_sizes, int n_in,
                              void* d_out, int out_size, void* d_ws, size_t ws_size,
                              hipStream_t stream) {
  const float* X = (const float*)d_in[0];
  const int* Y = (const int*)d_in[1];
  float* ws = (float*)d_ws;
  float* out = (float*)d_out;

  hipMemsetAsync(ws, 0, NCOPY * PART_F * sizeof(float), stream);
  fused_kernel<<<dim3(XB, T_B), 960, 0, stream>>>(X, Y, ws);
  finalize_kernel<<<1, 64, 0, stream>>>(ws, out);
}

// Round 12
// 480.863 us; speedup vs baseline: 1.0053x; 1.0053x over previous
//
#include <hip/hip_runtime.h>
#include <math.h>

#define NPIX 262144      // 512*512
#define T_B 4
#define T_C 20
#define T_K 16
#define TILE 256         // k-depth per LDS tile
#define XB 128           // x-blocks per batch; 512 blocks -> 2 blocks/CU
#define NTILES (NPIX / TILE / XB)   // 8
#define NCOPY 8          // atomic contention spreading
#define GRAM_F 960       // 4b * 15 pair-blocks * 16
#define PART_F 1200      // + 4b * 20c * 3 slots

__device__ __forceinline__ float wave_red(float v) {
#pragma unroll
  for (int off = 32; off > 0; off >>= 1) v += __shfl_xor(v, off, 64);
  return v;
}
// packed index of 4x4 channel block (I,J), I<=J, upper-tri of 5x5 grid; pb_idx(I,J)==wv
__device__ __forceinline__ int pb_idx(int I, int J) { return I * (11 - I) / 2 + (J - I); }

// v4 = R6's measured-good body (44 VGPR, no spill, TWO barriers per tile,
// SINGLE LDS buffer) with exactly one change: XB 64->128 (2 blocks/CU).
// R8/R11 evidence: the 1-barrier double-buffer variant explodes register
// pressure (compiler pipelines across iters -> 64 VGPR cap + ~1GB scratch).
// Keep the 2-barrier structure; get overlap from the co-resident block.
__global__ __launch_bounds__(960) void fused_kernel(const float* __restrict__ X,
                                                    const int* __restrict__ Y,
                                                    float* __restrict__ pw) {
  __shared__ float xs[T_C][TILE];  // 20 KB, single buffer
  const int tid = threadIdx.x, wv = tid >> 6, ln = tid & 63;
  const int b = blockIdx.y, xb = blockIdx.x;
  const int copy = xb & (NCOPY - 1);
  const float* Xb = X + (size_t)b * T_C * NPIX;
  const int*   Yb = Y + (size_t)b * T_C * NPIX;

  int I = 0, w = wv;
  while (w >= 5 - I) { w -= 5 - I; ++I; }
  const int J = I + w, rowA = 4 * I, rowB = 4 * J;

  const int c0 = wv;              // 0..14 (always <16: Y needed)
  const bool has2 = (wv < 5);
  const int c1 = 15 + wv;         // 15..19
  const bool y1 = (wv == 0);      // c1==15 still needs Y

  const float* x0p = Xb + (size_t)c0 * NPIX + ln * 4;
  const int*   y0p = Yb + (size_t)c0 * NPIX + ln * 4;
  const float* x1p = Xb + (size_t)c1 * NPIX + ln * 4;
  const int*   y1p = Yb + (size_t)c1 * NPIX + ln * 4;

  float acc[16];
#pragma unroll
  for (int m = 0; m < 16; ++m) acc[m] = 0.f;
  float sxy0 = 0.f, sy0 = 0.f, sb0 = 0.f;
  float sxy1 = 0.f, sy1 = 0.f, sb1 = 0.f, sx1 = 0.f;

  // prologue loads (tile 0 of this block)
  int k0 = xb * TILE;
  float4 xr0 = *(const float4*)(x0p + k0);
  int4   yr0 = *(const int4*)(y0p + k0);
  float4 xr1; int4 yr1;
  if (has2) xr1 = *(const float4*)(x1p + k0);
  if (y1)   yr1 = *(const int4*)(y1p + k0);

  for (int t = 0; t < NTILES; ++t) {
    // write staged regs to LDS
    *(float4*)&xs[c0][ln * 4] = xr0;
    if (has2) *(float4*)&xs[c1][ln * 4] = xr1;

    // stats from the staged registers (free ride on the staging pass)
    {
      float xv[4] = {xr0.x, xr0.y, xr0.z, xr0.w};
      int   yv[4] = {yr0.x, yr0.y, yr0.z, yr0.w};
#pragma unroll
      for (int u = 0; u < 4; ++u) {
        float fy = (float)yv[u];
        sxy0 = fmaf(fy, xv[u], sxy0);
        sy0 += fy;
        // y*log(x) + (1-y)*log1p(-x), y in {0,1}  ==  log(y ? x : 1-x)
        sb0 += __logf(yv[u] ? xv[u] : 1.f - xv[u]);
      }
    }
    if (has2) {
      float xv[4] = {xr1.x, xr1.y, xr1.z, xr1.w};
      if (y1) {
        int yv[4] = {yr1.x, yr1.y, yr1.z, yr1.w};
#pragma unroll
        for (int u = 0; u < 4; ++u) {
          float fy = (float)yv[u];
          sxy1 = fmaf(fy, xv[u], sxy1);
          sy1 += fy;
          sb1 += __logf(yv[u] ? xv[u] : 1.f - xv[u]);
        }
      } else {
        sx1 += (xv[0] + xv[1]) + (xv[2] + xv[3]);
      }
    }

    // issue next tile's global loads (latency hides under barrier+gram,
    // and under the co-resident block)
    if (t + 1 < NTILES) {
      int k0n = (xb + (t + 1) * XB) * TILE;
      xr0 = *(const float4*)(x0p + k0n);
      yr0 = *(const int4*)(y0p + k0n);
      if (has2) xr1 = *(const float4*)(x1p + k0n);
      if (y1)   yr1 = *(const int4*)(y1p + k0n);
    }
    __syncthreads();

    // gram compute on current LDS tile
    const int k = ln * 4;
    float4 av[4], bv[4];
#pragma unroll
    for (int r = 0; r < 4; ++r) av[r] = *(const float4*)&xs[rowA + r][k];
#pragma unroll
    for (int r = 0; r < 4; ++r) bv[r] = *(const float4*)&xs[rowB + r][k];
#pragma unroll
    for (int r = 0; r < 4; ++r)
#pragma unroll
      for (int q = 0; q < 4; ++q)
        acc[r * 4 + q] += (av[r].x * bv[q].x + av[r].y * bv[q].y) +
                          (av[r].z * bv[q].z + av[r].w * bv[q].w);
    __syncthreads();
  }

  // partial outputs: 8-way copy spreading
  float* pc = pw + copy * PART_F;
#pragma unroll
  for (int m = 0; m < 16; ++m) {
    float v = wave_red(acc[m]);
    if (ln == 0) atomicAdd(&pc[(b * 15 + wv) * 16 + m], v);
  }
  float v;
  v = wave_red(sxy0); if (ln == 0) atomicAdd(&pc[GRAM_F + (b * T_C + c0) * 3 + 0], v);
  v = wave_red(sy0);  if (ln == 0) atomicAdd(&pc[GRAM_F + (b * T_C + c0) * 3 + 1], v);
  v = wave_red(sb0);  if (ln == 0) atomicAdd(&pc[GRAM_F + (b * T_C + c0) * 3 + 2], v);
  if (has2) {
    if (y1) {
      v = wave_red(sxy1); if (ln == 0) atomicAdd(&pc[GRAM_F + (b * T_C + c1) * 3 + 0], v);
      v = wave_red(sy1);  if (ln == 0) atomicAdd(&pc[GRAM_F + (b * T_C + c1) * 3 + 1], v);
      v = wave_red(sb1);  if (ln == 0) atomicAdd(&pc[GRAM_F + (b * T_C + c1) * 3 + 2], v);
    } else {
      v = wave_red(sx1);  if (ln == 0) atomicAdd(&pc[GRAM_F + (b * T_C + c1) * 3 + 0], v);
    }
  }
}

// ---------------- finalize: sum 8 copies (float4), compute 4 scalars ----------------
__global__ __launch_bounds__(64) void finalize_kernel(const float* __restrict__ pw,
                                                      float* __restrict__ out) {
  __shared__ __align__(16) float red[PART_F];
  const int ln = threadIdx.x;
  for (int o4 = ln; o4 < PART_F / 4; o4 += 64) {
    float4 s = {0.f, 0.f, 0.f, 0.f};
#pragma unroll
    for (int c8 = 0; c8 < NCOPY; ++c8) {
      float4 vv = *(const float4*)(pw + c8 * PART_F + o4 * 4);
      s.x += vv.x; s.y += vv.y; s.z += vv.z; s.w += vv.w;
    }
    *(float4*)&red[o4 * 4] = s;
  }
  __syncthreads();
  const float invBN = 1.f / (4.f * 262144.f);

  // loss3
  float l3p = 0.f;
  for (int ij = ln; ij < 400; ij += 64) {
    const int i = ij / 20, j = ij % 20;
    if (i == j) continue;
    const int Ii = i >> 2, ri = i & 3, Jj = j >> 2, rj = j & 3;
    float sum = 0.f;
#pragma unroll
    for (int b = 0; b < 4; ++b) {
      float g = (Ii <= Jj) ? red[(b * 15 + pb_idx(Ii, Jj)) * 16 + ri * 4 + rj]
                           : red[(b * 15 + pb_idx(Jj, Ii)) * 16 + rj * 4 + ri];
      float si = red[(b * 15 + pb_idx(Ii, Ii)) * 16 + ri * 5];
      float sj = red[(b * 15 + pb_idx(Jj, Jj)) * 16 + rj * 5];
      sum += (g + 1.f) / (si + sj + 1.f);
    }
    l3p += sum * 0.25f;
  }
  const float l3 = wave_red(l3p) / 380.f;

  // loss1: dice + bce, c<16
  float l1p = 0.f;
  if (ln < 16) {
    const int c = ln, Ic = c >> 2, rc = c & 3;
    float d = 0.f, bsum = 0.f;
#pragma unroll
    for (int b = 0; b < 4; ++b) {
      float num = red[GRAM_F + (b * T_C + c) * 3 + 0] + 1.f;
      float s = red[(b * 15 + pb_idx(Ic, Ic)) * 16 + rc * 5];      // sum x^2 (gram diag)
      float den = s + red[GRAM_F + (b * T_C + c) * 3 + 1] + 1.f;   // + sum y
      d += 1.f - num / den;
      bsum += red[GRAM_F + (b * T_C + c) * 3 + 2];
    }
    l1p = d * 0.25f - bsum * invBN;
  }
  const float l1 = wave_red(l1p) * (1.f / 16.f);

  // loss2: c>=16
  float l2p = 0.f;
  if (ln >= 16 && ln < 20) {
    float s = 0.f;
#pragma unroll
    for (int b = 0; b < 4; ++b) s += red[GRAM_F + (b * T_C + ln) * 3 + 0];
    float m = s * invBN;
    float vv = fminf(fmaxf(m * 50.f, 0.f), 1.f);
    l2p = -logf(vv);
  }
  const float l2 = wave_red(l2p) * 0.25f;

  if (ln == 0) {
    out[1] = l1; out[2] = l2; out[3] = l3;
    out[0] = 0.1f * (l1 + l2 + l3);
  }
}

extern "C" void kernel_launch(void* const* d_in, const int* in_sizes, int n_in,
                              void* d_out, int out_size, void* d_ws, size_t ws_size,
                              hipStream_t stream) {
  const float* X = (const float*)d_in[0];
  const int* Y = (const int*)d_in[1];
  float* ws = (float*)d_ws;
  float* out = (float*)d_out;

  hipMemsetAsync(ws, 0, NCOPY * PART_F * sizeof(float), stream);
  fused_kernel<<<dim3(XB, T_B), 960, 0, stream>>>(X, Y, ws);
  finalize_kernel<<<1, 64, 0, stream>>>(ws, out);
}

// Round 13
// 209.201 us; speedup vs baseline: 2.3109x; 2.2986x over previous
//
#include <hip/hip_runtime.h>
#include <math.h>

#define NPIX 262144      // 512*512
#define T_B 4
#define T_C 20
#define T_K 16
#define TILE 256         // k-depth per LDS tile
#define XB 128           // x-blocks per batch; 512 blocks -> 2 blocks/CU
#define NTILES (NPIX / TILE / XB)   // 8
#define NCOPY 8          // atomic contention spreading
#define GRAM_F 960       // 4b * 15 pair-blocks * 16
#define PART_F 1200      // + 4b * 20c * 3 slots

__device__ __forceinline__ float wave_red(float v) {
#pragma unroll
  for (int off = 32; off > 0; off >>= 1) v += __shfl_xor(v, off, 64);
  return v;
}
// packed index of 4x4 channel block (I,J), I<=J, upper-tri of 5x5 grid; pb_idx(I,J)==wv
__device__ __forceinline__ int pb_idx(int I, int J) { return I * (11 - I) / 2 + (J - I); }

// v5 = v4 + "#pragma unroll 1" on the tile loop.
// R6/R11/R12 triplet isolated the spill variable: NTILES=16 (R6) -> rolled
// loop, 44 VGPR, no spill; NTILES=8 (R11 dbuf AND R12 single-buf) -> full
// unroll, 64 VGPR, ~1 GB scratch traffic. Buffering scheme was innocent.
// Pin the loop rolled; keep XB=128 to finally test 2-blocks/CU overlap.
__global__ __launch_bounds__(960) void fused_kernel(const float* __restrict__ X,
                                                    const int* __restrict__ Y,
                                                    float* __restrict__ pw) {
  __shared__ float xs[T_C][TILE];  // 20 KB, single buffer
  const int tid = threadIdx.x, wv = tid >> 6, ln = tid & 63;
  const int b = blockIdx.y, xb = blockIdx.x;
  const int copy = xb & (NCOPY - 1);
  const float* Xb = X + (size_t)b * T_C * NPIX;
  const int*   Yb = Y + (size_t)b * T_C * NPIX;

  int I = 0, w = wv;
  while (w >= 5 - I) { w -= 5 - I; ++I; }
  const int J = I + w, rowA = 4 * I, rowB = 4 * J;

  const int c0 = wv;              // 0..14 (always <16: Y needed)
  const bool has2 = (wv < 5);
  const int c1 = 15 + wv;         // 15..19
  const bool y1 = (wv == 0);      // c1==15 still needs Y

  const float* x0p = Xb + (size_t)c0 * NPIX + ln * 4;
  const int*   y0p = Yb + (size_t)c0 * NPIX + ln * 4;
  const float* x1p = Xb + (size_t)c1 * NPIX + ln * 4;
  const int*   y1p = Yb + (size_t)c1 * NPIX + ln * 4;

  float acc[16];
#pragma unroll
  for (int m = 0; m < 16; ++m) acc[m] = 0.f;
  float sxy0 = 0.f, sy0 = 0.f, sb0 = 0.f;
  float sxy1 = 0.f, sy1 = 0.f, sb1 = 0.f, sx1 = 0.f;

  // prologue loads (tile 0 of this block)
  int k0 = xb * TILE;
  float4 xr0 = *(const float4*)(x0p + k0);
  int4   yr0 = *(const int4*)(y0p + k0);
  float4 xr1; int4 yr1;
  if (has2) xr1 = *(const float4*)(x1p + k0);
  if (y1)   yr1 = *(const int4*)(y1p + k0);

#pragma unroll 1   // CRITICAL: full unroll at NTILES=8 caused 64-VGPR + 1GB spill
  for (int t = 0; t < NTILES; ++t) {
    // write staged regs to LDS
    *(float4*)&xs[c0][ln * 4] = xr0;
    if (has2) *(float4*)&xs[c1][ln * 4] = xr1;

    // stats from the staged registers (free ride on the staging pass)
    {
      float xv[4] = {xr0.x, xr0.y, xr0.z, xr0.w};
      int   yv[4] = {yr0.x, yr0.y, yr0.z, yr0.w};
#pragma unroll
      for (int u = 0; u < 4; ++u) {
        float fy = (float)yv[u];
        sxy0 = fmaf(fy, xv[u], sxy0);
        sy0 += fy;
        // y*log(x) + (1-y)*log1p(-x), y in {0,1}  ==  log(y ? x : 1-x)
        sb0 += __logf(yv[u] ? xv[u] : 1.f - xv[u]);
      }
    }
    if (has2) {
      float xv[4] = {xr1.x, xr1.y, xr1.z, xr1.w};
      if (y1) {
        int yv[4] = {yr1.x, yr1.y, yr1.z, yr1.w};
#pragma unroll
        for (int u = 0; u < 4; ++u) {
          float fy = (float)yv[u];
          sxy1 = fmaf(fy, xv[u], sxy1);
          sy1 += fy;
          sb1 += __logf(yv[u] ? xv[u] : 1.f - xv[u]);
        }
      } else {
        sx1 += (xv[0] + xv[1]) + (xv[2] + xv[3]);
      }
    }

    // issue next tile's global loads (latency hides under barrier+gram,
    // and under the co-resident block)
    if (t + 1 < NTILES) {
      int k0n = (xb + (t + 1) * XB) * TILE;
      xr0 = *(const float4*)(x0p + k0n);
      yr0 = *(const int4*)(y0p + k0n);
      if (has2) xr1 = *(const float4*)(x1p + k0n);
      if (y1)   yr1 = *(const int4*)(y1p + k0n);
    }
    __syncthreads();

    // gram compute on current LDS tile
    const int k = ln * 4;
    float4 av[4], bv[4];
#pragma unroll
    for (int r = 0; r < 4; ++r) av[r] = *(const float4*)&xs[rowA + r][k];
#pragma unroll
    for (int r = 0; r < 4; ++r) bv[r] = *(const float4*)&xs[rowB + r][k];
#pragma unroll
    for (int r = 0; r < 4; ++r)
#pragma unroll
      for (int q = 0; q < 4; ++q)
        acc[r * 4 + q] += (av[r].x * bv[q].x + av[r].y * bv[q].y) +
                          (av[r].z * bv[q].z + av[r].w * bv[q].w);
    __syncthreads();
  }

  // partial outputs: 8-way copy spreading
  float* pc = pw + copy * PART_F;
#pragma unroll
  for (int m = 0; m < 16; ++m) {
    float v = wave_red(acc[m]);
    if (ln == 0) atomicAdd(&pc[(b * 15 + wv) * 16 + m], v);
  }
  float v;
  v = wave_red(sxy0); if (ln == 0) atomicAdd(&pc[GRAM_F + (b * T_C + c0) * 3 + 0], v);
  v = wave_red(sy0);  if (ln == 0) atomicAdd(&pc[GRAM_F + (b * T_C + c0) * 3 + 1], v);
  v = wave_red(sb0);  if (ln == 0) atomicAdd(&pc[GRAM_F + (b * T_C + c0) * 3 + 2], v);
  if (has2) {
    if (y1) {
      v = wave_red(sxy1); if (ln == 0) atomicAdd(&pc[GRAM_F + (b * T_C + c1) * 3 + 0], v);
      v = wave_red(sy1);  if (ln == 0) atomicAdd(&pc[GRAM_F + (b * T_C + c1) * 3 + 1], v);
      v = wave_red(sb1);  if (ln == 0) atomicAdd(&pc[GRAM_F + (b * T_C + c1) * 3 + 2], v);
    } else {
      v = wave_red(sx1);  if (ln == 0) atomicAdd(&pc[GRAM_F + (b * T_C + c1) * 3 + 0], v);
    }
  }
}

// ---------------- finalize: sum 8 copies (float4), compute 4 scalars ----------------
__global__ __launch_bounds__(64) void finalize_kernel(const float* __restrict__ pw,
                                                      float* __restrict__ out) {
  __shared__ __align__(16) float red[PART_F];
  const int ln = threadIdx.x;
  for (int o4 = ln; o4 < PART_F / 4; o4 += 64) {
    float4 s = {0.f, 0.f, 0.f, 0.f};
#pragma unroll
    for (int c8 = 0; c8 < NCOPY; ++c8) {
      float4 vv = *(const float4*)(pw + c8 * PART_F + o4 * 4);
      s.x += vv.x; s.y += vv.y; s.z += vv.z; s.w += vv.w;
    }
    *(float4*)&red[o4 * 4] = s;
  }
  __syncthreads();
  const float invBN = 1.f / (4.f * 262144.f);

  // loss3
  float l3p = 0.f;
  for (int ij = ln; ij < 400; ij += 64) {
    const int i = ij / 20, j = ij % 20;
    if (i == j) continue;
    const int Ii = i >> 2, ri = i & 3, Jj = j >> 2, rj = j & 3;
    float sum = 0.f;
#pragma unroll
    for (int b = 0; b < 4; ++b) {
      float g = (Ii <= Jj) ? red[(b * 15 + pb_idx(Ii, Jj)) * 16 + ri * 4 + rj]
                           : red[(b * 15 + pb_idx(Jj, Ii)) * 16 + rj * 4 + ri];
      float si = red[(b * 15 + pb_idx(Ii, Ii)) * 16 + ri * 5];
      float sj = red[(b * 15 + pb_idx(Jj, Jj)) * 16 + rj * 5];
      sum += (g + 1.f) / (si + sj + 1.f);
    }
    l3p += sum * 0.25f;
  }
  const float l3 = wave_red(l3p) / 380.f;

  // loss1: dice + bce, c<16
  float l1p = 0.f;
  if (ln < 16) {
    const int c = ln, Ic = c >> 2, rc = c & 3;
    float d = 0.f, bsum = 0.f;
#pragma unroll
    for (int b = 0; b < 4; ++b) {
      float num = red[GRAM_F + (b * T_C + c) * 3 + 0] + 1.f;
      float s = red[(b * 15 + pb_idx(Ic, Ic)) * 16 + rc * 5];      // sum x^2 (gram diag)
      float den = s + red[GRAM_F + (b * T_C + c) * 3 + 1] + 1.f;   // + sum y
      d += 1.f - num / den;
      bsum += red[GRAM_F + (b * T_C + c) * 3 + 2];
    }
    l1p = d * 0.25f - bsum * invBN;
  }
  const float l1 = wave_red(l1p) * (1.f / 16.f);

  // loss2: c>=16
  float l2p = 0.f;
  if (ln >= 16 && ln < 20) {
    float s = 0.f;
#pragma unroll
    for (int b = 0; b < 4; ++b) s += red[GRAM_F + (b * T_C + ln) * 3 + 0];
    float m = s * invBN;
    float vv = fminf(fmaxf(m * 50.f, 0.f), 1.f);
    l2p = -logf(vv);
  }
  const float l2 = wave_red(l2p) * 0.25f;

  if (ln == 0) {
    out[1] = l1; out[2] = l2; out[3] = l3;
    out[0] = 0.1f * (l1 + l2 + l3);
  }
}

extern "C" void kernel_launch(void* const* d_in, const int* in_sizes, int n_in,
                              void* d_out, int out_size, void* d_ws, size_t ws_size,
                              hipStream_t stream) {
  const float* X = (const float*)d_in[0];
  const int* Y = (const int*)d_in[1];
  float* ws = (float*)d_ws;
  float* out = (float*)d_out;

  hipMemsetAsync(ws, 0, NCOPY * PART_F * sizeof(float), stream);
  fused_kernel<<<dim3(XB, T_B), 960, 0, stream>>>(X, Y, ws);
  finalize_kernel<<<1, 64, 0, stream>>>(ws, out);
}